// Round 1
// baseline (519.241 us; speedup 1.0000x reference)
//
#include <hip/hip_runtime.h>
#include <math.h>

#define B_   4
#define L_   4096
#define D_   512
#define F_   512
#define CHK  256
#define NC   (L_ / CHK)   // 16
#define EPSF 1e-8f

__device__ __forceinline__ float phi_map(float x) { return x > 0.0f ? x + 1.0f : expf(x); }

// ---------------------------------------------------------------------------
// Z_local[b,c,f] = sum_{j in chunk} phi(K[b, c*CHK+j, f])
__global__ __launch_bounds__(256) void zlocal_k(const float* __restrict__ keys,
                                                float* __restrict__ Z) {
    int bc = blockIdx.y;
    int b = bc / NC, c = bc % NC;
    int f = blockIdx.x * 256 + threadIdx.x;
    const float* kp = keys + ((size_t)b * L_ + (size_t)c * CHK) * F_ + f;
    float s0 = 0.f, s1 = 0.f, s2 = 0.f, s3 = 0.f;
    for (int j = 0; j < CHK; j += 4) {
        s0 += phi_map(kp[(size_t)(j + 0) * F_]);
        s1 += phi_map(kp[(size_t)(j + 1) * F_]);
        s2 += phi_map(kp[(size_t)(j + 2) * F_]);
        s3 += phi_map(kp[(size_t)(j + 3) * F_]);
    }
    Z[(size_t)bc * F_ + f] = (s0 + s1) + (s2 + s3);
}

// Exclusive prefix over chunks, in place: Z[b,c,f] -> sum_{c'<c} Z[b,c',f]
__global__ __launch_bounds__(256) void zscan_k(float* __restrict__ Z) {
    int t = blockIdx.x * 256 + threadIdx.x;   // B*F threads
    int b = t / F_, f = t % F_;
    float tmp[NC];
    for (int c = 0; c < NC; c++) tmp[c] = Z[((size_t)(b * NC + c)) * F_ + f];
    float run = 0.f;
    for (int c = 0; c < NC; c++) {
        Z[((size_t)(b * NC + c)) * F_ + f] = run;
        run += tmp[c];
    }
}

// S_local[b,c,f,d] = sum_{j in chunk} phi(K[j,f]) * V[j,d]   (GEMM M=F,N=D,K=CHK)
__global__ __launch_bounds__(256) void slocal_k(const float* __restrict__ keys,
                                                const float* __restrict__ vals,
                                                float* __restrict__ S) {
    int bc = blockIdx.z;
    int b = bc / NC, c = bc % NC;
    int ft0 = blockIdx.y * 64, dt0 = blockIdx.x * 64;
    __shared__ float Ks[16][64];
    __shared__ float Vs[16][64];
    int tid = threadIdx.x, ty = tid >> 4, tx = tid & 15;
    float acc[4][4] = {};
    const float* kbase = keys + ((size_t)b * L_ + (size_t)c * CHK) * F_;
    const float* vbase = vals + ((size_t)b * L_ + (size_t)c * CHK) * D_;
    for (int j0 = 0; j0 < CHK; j0 += 16) {
        int row = tid >> 4, c4 = (tid & 15) * 4;
        float4 kv = *reinterpret_cast<const float4*>(&kbase[(size_t)(j0 + row) * F_ + ft0 + c4]);
        Ks[row][c4 + 0] = phi_map(kv.x);
        Ks[row][c4 + 1] = phi_map(kv.y);
        Ks[row][c4 + 2] = phi_map(kv.z);
        Ks[row][c4 + 3] = phi_map(kv.w);
        float4 vv = *reinterpret_cast<const float4*>(&vbase[(size_t)(j0 + row) * D_ + dt0 + c4]);
        *reinterpret_cast<float4*>(&Vs[row][c4]) = vv;
        __syncthreads();
        #pragma unroll
        for (int kk = 0; kk < 16; kk++) {
            float4 a = *reinterpret_cast<const float4*>(&Ks[kk][ty * 4]);
            float4 bb = *reinterpret_cast<const float4*>(&Vs[kk][tx * 4]);
            float av[4] = {a.x, a.y, a.z, a.w};
            float bv[4] = {bb.x, bb.y, bb.z, bb.w};
            #pragma unroll
            for (int i = 0; i < 4; i++)
                #pragma unroll
                for (int j = 0; j < 4; j++) acc[i][j] += av[i] * bv[j];
        }
        __syncthreads();
    }
    float* Sp = S + (size_t)bc * F_ * D_;
    for (int i = 0; i < 4; i++) {
        int f = ft0 + ty * 4 + i;
        float4 st = {acc[i][0], acc[i][1], acc[i][2], acc[i][3]};
        *reinterpret_cast<float4*>(&Sp[(size_t)f * D_ + dt0 + tx * 4]) = st;
    }
}

// Exclusive prefix over chunks for S, in place.
__global__ __launch_bounds__(256) void sscan_k(float* __restrict__ S) {
    size_t t = (size_t)blockIdx.x * 256 + threadIdx.x;   // B*F*D threads
    int b = (int)(t / (F_ * D_));
    int fd = (int)(t % (F_ * D_));
    float tmp[NC];
    for (int c = 0; c < NC; c++) tmp[c] = S[((size_t)(b * NC + c)) * F_ * D_ + fd];
    float run = 0.f;
    for (int c = 0; c < NC; c++) {
        S[((size_t)(b * NC + c)) * F_ * D_ + fd] = run;
        run += tmp[c];
    }
}

// A[b,c,i,j] = (i>=j) ? sum_f phi(Q[i,f])*phi(K[j,f]) : 0    (lower tiles only)
__global__ __launch_bounds__(256) void amat_k(const float* __restrict__ q,
                                              const float* __restrict__ keys,
                                              float* __restrict__ A) {
    int bc = blockIdx.y;
    int b = bc / NC, c = bc % NC;
    int t = blockIdx.x;                       // 0..9 -> lower-triangular 64x64 tile
    int it = (t >= 6) ? 3 : (t >= 3) ? 2 : (t >= 1) ? 1 : 0;
    int jt = t - it * (it + 1) / 2;
    int i0 = it * 64, j0 = jt * 64;
    __shared__ float Qs[64][17];
    __shared__ float Ks2[64][17];
    int tid = threadIdx.x, ty = tid >> 4, tx = tid & 15;
    float acc[4][4] = {};
    const float* qbase = q + ((size_t)b * L_ + (size_t)c * CHK + i0) * F_;
    const float* kbase = keys + ((size_t)b * L_ + (size_t)c * CHK + j0) * F_;
    for (int f0 = 0; f0 < F_; f0 += 16) {
        int row = tid >> 2, c4 = (tid & 3) * 4;
        float4 qv = *reinterpret_cast<const float4*>(&qbase[(size_t)row * F_ + f0 + c4]);
        Qs[row][c4 + 0] = phi_map(qv.x);
        Qs[row][c4 + 1] = phi_map(qv.y);
        Qs[row][c4 + 2] = phi_map(qv.z);
        Qs[row][c4 + 3] = phi_map(qv.w);
        float4 kv = *reinterpret_cast<const float4*>(&kbase[(size_t)row * F_ + f0 + c4]);
        Ks2[row][c4 + 0] = phi_map(kv.x);
        Ks2[row][c4 + 1] = phi_map(kv.y);
        Ks2[row][c4 + 2] = phi_map(kv.z);
        Ks2[row][c4 + 3] = phi_map(kv.w);
        __syncthreads();
        #pragma unroll
        for (int kk = 0; kk < 16; kk++) {
            float av[4], bv[4];
            #pragma unroll
            for (int i = 0; i < 4; i++) av[i] = Qs[ty * 4 + i][kk];
            #pragma unroll
            for (int j = 0; j < 4; j++) bv[j] = Ks2[tx * 4 + j][kk];
            #pragma unroll
            for (int i = 0; i < 4; i++)
                #pragma unroll
                for (int j = 0; j < 4; j++) acc[i][j] += av[i] * bv[j];
        }
        __syncthreads();
    }
    float* Ap = A + (size_t)bc * CHK * CHK;
    for (int i = 0; i < 4; i++) {
        int gi = i0 + ty * 4 + i;
        int gj = j0 + tx * 4;
        float4 st;
        st.x = (gi >= gj + 0) ? acc[i][0] : 0.f;
        st.y = (gi >= gj + 1) ? acc[i][1] : 0.f;
        st.z = (gi >= gj + 2) ? acc[i][2] : 0.f;
        st.w = (gi >= gj + 3) ? acc[i][3] : 0.f;
        *reinterpret_cast<float4*>(&Ap[(size_t)gi * CHK + gj]) = st;
    }
}

// out = (phiQ @ S_prefix + A @ V) / max(phiQ·Z_prefix + rowsum(A), EPS)
__global__ __launch_bounds__(256) void out_k(const float* __restrict__ q,
                                             const float* __restrict__ vals,
                                             const float* __restrict__ S,
                                             const float* __restrict__ A,
                                             const float* __restrict__ Z,
                                             float* __restrict__ out) {
    int bc = blockIdx.z;
    int b = bc / NC, c = bc % NC;
    int rt = blockIdx.y;
    int dt0 = blockIdx.x * 64;
    int r0 = rt * 64;
    __shared__ float Ls[64][17];   // phiQ rows or A rows
    __shared__ float Rs[16][64];   // S or V tile
    __shared__ float Zs[16];
    int tid = threadIdx.x, ty = tid >> 4, tx = tid & 15;
    float acc[4][4] = {};
    float qz[4] = {};
    float rs[4] = {};
    const float* qbase = q + ((size_t)b * L_ + (size_t)c * CHK + r0) * F_;

    if (c > 0) {   // inter-chunk: phiQ @ S_excl, den += phiQ·Z_excl
        const float* Sp = S + (size_t)bc * F_ * D_;
        const float* Zp = Z + (size_t)bc * F_;
        for (int f0 = 0; f0 < F_; f0 += 16) {
            int row = tid >> 2, c4 = (tid & 3) * 4;
            float4 qv = *reinterpret_cast<const float4*>(&qbase[(size_t)row * F_ + f0 + c4]);
            Ls[row][c4 + 0] = phi_map(qv.x);
            Ls[row][c4 + 1] = phi_map(qv.y);
            Ls[row][c4 + 2] = phi_map(qv.z);
            Ls[row][c4 + 3] = phi_map(qv.w);
            int row2 = tid >> 4, d4 = (tid & 15) * 4;
            float4 sv = *reinterpret_cast<const float4*>(&Sp[(size_t)(f0 + row2) * D_ + dt0 + d4]);
            *reinterpret_cast<float4*>(&Rs[row2][d4]) = sv;
            if (tid < 16) Zs[tid] = Zp[f0 + tid];
            __syncthreads();
            #pragma unroll
            for (int kk = 0; kk < 16; kk++) {
                float av[4];
                #pragma unroll
                for (int i = 0; i < 4; i++) av[i] = Ls[ty * 4 + i][kk];
                float4 bb = *reinterpret_cast<const float4*>(&Rs[kk][tx * 4]);
                float bv[4] = {bb.x, bb.y, bb.z, bb.w};
                float zk = Zs[kk];
                #pragma unroll
                for (int i = 0; i < 4; i++) {
                    qz[i] += av[i] * zk;
                    #pragma unroll
                    for (int j = 0; j < 4; j++) acc[i][j] += av[i] * bv[j];
                }
            }
            __syncthreads();
        }
    }

    // intra-chunk: A @ V (only j-tiles <= rt are nonzero), den += rowsum(A)
    const float* Ap = A + (size_t)bc * CHK * CHK;
    const float* vbase = vals + ((size_t)b * L_ + (size_t)c * CHK) * D_;
    for (int j0 = 0; j0 < (rt + 1) * 64; j0 += 16) {
        int row = tid >> 2, c4 = (tid & 3) * 4;
        float4 av4 = *reinterpret_cast<const float4*>(&Ap[(size_t)(r0 + row) * CHK + j0 + c4]);
        Ls[row][c4 + 0] = av4.x;
        Ls[row][c4 + 1] = av4.y;
        Ls[row][c4 + 2] = av4.z;
        Ls[row][c4 + 3] = av4.w;
        int row2 = tid >> 4, d4 = (tid & 15) * 4;
        float4 vv = *reinterpret_cast<const float4*>(&vbase[(size_t)(j0 + row2) * D_ + dt0 + d4]);
        *reinterpret_cast<float4*>(&Rs[row2][d4]) = vv;
        __syncthreads();
        #pragma unroll
        for (int kk = 0; kk < 16; kk++) {
            float av[4];
            #pragma unroll
            for (int i = 0; i < 4; i++) av[i] = Ls[ty * 4 + i][kk];
            float4 bb = *reinterpret_cast<const float4*>(&Rs[kk][tx * 4]);
            float bv[4] = {bb.x, bb.y, bb.z, bb.w};
            #pragma unroll
            for (int i = 0; i < 4; i++) {
                rs[i] += av[i];
                #pragma unroll
                for (int j = 0; j < 4; j++) acc[i][j] += av[i] * bv[j];
            }
        }
        __syncthreads();
    }

    float* obase = out + ((size_t)b * L_ + (size_t)c * CHK + r0) * D_ + dt0;
    for (int i = 0; i < 4; i++) {
        float dd = fmaxf(qz[i] + rs[i], EPSF);
        float inv = 1.0f / dd;
        float4 st = {acc[i][0] * inv, acc[i][1] * inv, acc[i][2] * inv, acc[i][3] * inv};
        *reinterpret_cast<float4*>(&obase[(size_t)(ty * 4 + i) * D_ + tx * 4]) = st;
    }
}

extern "C" void kernel_launch(void* const* d_in, const int* in_sizes, int n_in,
                              void* d_out, int out_size, void* d_ws, size_t ws_size,
                              hipStream_t stream) {
    const float* q = (const float*)d_in[0];
    const float* k = (const float*)d_in[1];
    const float* v = (const float*)d_in[2];
    float* out = (float*)d_out;

    // workspace layout (fp32): S[B*NC*F*D] | A[B*NC*CHK*CHK] | Z[B*NC*F]
    size_t nS = (size_t)B_ * NC * F_ * D_;
    size_t nA = (size_t)B_ * NC * CHK * CHK;
    size_t nZ = (size_t)B_ * NC * F_;
    size_t need = (nS + nA + nZ) * sizeof(float);
    if (ws_size < need) return;   // insufficient scratch; fail loudly via validation

    float* S = (float*)d_ws;
    float* A = S + nS;
    float* Z = A + nA;

    zlocal_k<<<dim3(F_ / 256, B_ * NC), 256, 0, stream>>>(k, Z);
    slocal_k<<<dim3(D_ / 64, F_ / 64, B_ * NC), 256, 0, stream>>>(k, v, S);
    amat_k<<<dim3(10, B_ * NC), 256, 0, stream>>>(q, k, A);
    zscan_k<<<dim3((B_ * F_) / 256), 256, 0, stream>>>(Z);
    sscan_k<<<dim3((B_ * F_ * D_) / 256), 256, 0, stream>>>(S);
    out_k<<<dim3(D_ / 64, CHK / 64, B_ * NC), 256, 0, stream>>>(q, v, S, A, Z, out);
}

// Round 2
// 201.878 us; speedup vs baseline: 2.5720x; 2.5720x over previous
//
#include <hip/hip_runtime.h>
#include <math.h>

#define B_   4
#define L_   4096
#define D_   512
#define F_   512
#define CHK  256
#define NC   (L_ / CHK)   // 16
#define EPSF 1e-8f

typedef unsigned short ushort_t;
using bf16x8 = __attribute__((ext_vector_type(8))) short;
using f32x4  = __attribute__((ext_vector_type(4))) float;
using u16x4  = __attribute__((ext_vector_type(4))) unsigned short;
using u16x8  = __attribute__((ext_vector_type(8))) unsigned short;

__device__ __forceinline__ float phi_map(float x) { return x > 0.0f ? x + 1.0f : expf(x); }

__device__ __forceinline__ ushort_t f2b(float f) {
    union { float f; unsigned int u; } v; v.f = f;
    unsigned int r = v.u + 0x7FFFu + ((v.u >> 16) & 1u);
    return (ushort_t)(r >> 16);
}
__device__ __forceinline__ float b2f(ushort_t h) {
    union { unsigned int u; float f; } v; v.u = ((unsigned int)h) << 16;
    return v.f;
}

// ===========================================================================
// NEW bf16-MFMA PATH
// ws layout (ushort elems): phiQ | phiK | phiKT | Vt | Stp | Amat | Zp, then Zloc fp32.
// phiQ  [B][L][F]  row-major (k=f innermost)  : A-operand for amat + out-inter
// phiK  [B][L][F]  row-major                  : B-operand for amat ([n=j][k=f])
// phiKT [B][F][L]                             : B-operand for sloc ([n=f][k=j])
// Vt    [B][D][L]                             : A-op sloc ([m=d][k=j]), B-op out-intra ([n=d][k=j])
// Stp   [B][NC][D][F] bf16 exclusive prefix   : B-operand for out-inter ([n=d][k=f])
// Amat  [B][NC][CHK][CHK] bf16 (tril)         : A-operand for out-intra ([m=i][k=j])
// Zp    [B][NC][F] bf16 exclusive prefix
// ===========================================================================

// φ(Q) elementwise, fp32 -> bf16
__global__ __launch_bounds__(256) void prepq_k(const float* __restrict__ q,
                                               ushort_t* __restrict__ phiQ) {
    size_t i = ((size_t)blockIdx.x * 256 + threadIdx.x) * 8;
    float4 a = *reinterpret_cast<const float4*>(q + i);
    float4 b = *reinterpret_cast<const float4*>(q + i + 4);
    u16x8 o;
    o[0] = f2b(phi_map(a.x)); o[1] = f2b(phi_map(a.y));
    o[2] = f2b(phi_map(a.z)); o[3] = f2b(phi_map(a.w));
    o[4] = f2b(phi_map(b.x)); o[5] = f2b(phi_map(b.y));
    o[6] = f2b(phi_map(b.z)); o[7] = f2b(phi_map(b.w));
    *reinterpret_cast<u16x8*>(phiQ + i) = o;
}

// φ(K): write row-major phiK AND transposed phiKT via LDS 64x64 tile
__global__ __launch_bounds__(256) void prepkt_k(const float* __restrict__ keys,
                                                ushort_t* __restrict__ phiK,
                                                ushort_t* __restrict__ phiKT) {
    int b = blockIdx.z, l0 = blockIdx.y * 64, f0 = blockIdx.x * 64;
    __shared__ ushort_t tile[64][66];
    int t = threadIdx.x;
    int tr = t >> 4, tc4 = (t & 15) * 4;
    #pragma unroll
    for (int r = 0; r < 4; r++) {
        int row = r * 16 + tr;
        float4 v = *reinterpret_cast<const float4*>(keys + ((size_t)(b * L_ + l0 + row)) * F_ + f0 + tc4);
        u16x4 p;
        p[0] = f2b(phi_map(v.x)); p[1] = f2b(phi_map(v.y));
        p[2] = f2b(phi_map(v.z)); p[3] = f2b(phi_map(v.w));
        tile[row][tc4 + 0] = p[0]; tile[row][tc4 + 1] = p[1];
        tile[row][tc4 + 2] = p[2]; tile[row][tc4 + 3] = p[3];
        *reinterpret_cast<u16x4*>(phiK + ((size_t)(b * L_ + l0 + row)) * F_ + f0 + tc4) = p;
    }
    __syncthreads();
    int fr = t & 63, lgp = t >> 6;
    u16x8 o0, o1;
    #pragma unroll
    for (int s = 0; s < 8; s++) { o0[s] = tile[lgp * 16 + s][fr]; o1[s] = tile[lgp * 16 + 8 + s][fr]; }
    ushort_t* dst = phiKT + ((size_t)(b * F_ + f0 + fr)) * L_ + l0 + lgp * 16;
    *reinterpret_cast<u16x8*>(dst) = o0;
    *reinterpret_cast<u16x8*>(dst + 8) = o1;
}

// V -> Vt (transpose only, bf16)
__global__ __launch_bounds__(256) void prepvt_k(const float* __restrict__ vals,
                                                ushort_t* __restrict__ Vt) {
    int b = blockIdx.z, l0 = blockIdx.y * 64, d0 = blockIdx.x * 64;
    __shared__ ushort_t tile[64][66];
    int t = threadIdx.x;
    int tr = t >> 4, tc4 = (t & 15) * 4;
    #pragma unroll
    for (int r = 0; r < 4; r++) {
        int row = r * 16 + tr;
        float4 v = *reinterpret_cast<const float4*>(vals + ((size_t)(b * L_ + l0 + row)) * D_ + d0 + tc4);
        tile[row][tc4 + 0] = f2b(v.x); tile[row][tc4 + 1] = f2b(v.y);
        tile[row][tc4 + 2] = f2b(v.z); tile[row][tc4 + 3] = f2b(v.w);
    }
    __syncthreads();
    int dr = t & 63, lgp = t >> 6;
    u16x8 o0, o1;
    #pragma unroll
    for (int s = 0; s < 8; s++) { o0[s] = tile[lgp * 16 + s][dr]; o1[s] = tile[lgp * 16 + 8 + s][dr]; }
    ushort_t* dst = Vt + ((size_t)(b * D_ + d0 + dr)) * L_ + l0 + lgp * 16;
    *reinterpret_cast<u16x8*>(dst) = o0;
    *reinterpret_cast<u16x8*>(dst + 8) = o1;
}

// Z_local[bc][f] = sum over chunk rows of phiK (fp32 accum)
__global__ __launch_bounds__(256) void zloc_k(const ushort_t* __restrict__ phiK,
                                              float* __restrict__ Zloc) {
    int bc = blockIdx.x, b = bc >> 4, c = bc & 15;
    int t = threadIdx.x;
    const ushort_t* base = phiK + ((size_t)(b * L_ + c * CHK)) * F_;
    float s0 = 0.f, s1 = 0.f;
    for (int l = 0; l < CHK; l++) {
        s0 += b2f(base[(size_t)l * F_ + t]);
        s1 += b2f(base[(size_t)l * F_ + 256 + t]);
    }
    Zloc[(size_t)bc * F_ + t] = s0;
    Zloc[(size_t)bc * F_ + 256 + t] = s1;
}

// exclusive prefix over chunks -> Zp bf16
__global__ __launch_bounds__(256) void zscan_k(const float* __restrict__ Zloc,
                                               ushort_t* __restrict__ Zp) {
    int g = blockIdx.x * 256 + threadIdx.x;   // B*F
    int b = g / F_, f = g % F_;
    float run = 0.f;
    for (int c = 0; c < NC; c++) {
        Zp[((size_t)(b * NC + c)) * F_ + f] = f2b(run);
        run += Zloc[((size_t)(b * NC + c)) * F_ + f];
    }
}

// Amat[bc][i][j] = tril( phiQ_chunk @ phiK_chunk^T ), bf16 out. 128x128 blocks.
__global__ __launch_bounds__(256) void amatm_k(const ushort_t* __restrict__ phiQ,
                                               const ushort_t* __restrict__ phiK,
                                               ushort_t* __restrict__ Amat) {
    int bc = blockIdx.z, b = bc >> 4, c = bc & 15;
    int it = blockIdx.y, jt = blockIdx.x;
    ushort_t* Ap = Amat + (size_t)bc * CHK * CHK;
    int t = threadIdx.x;
    if (jt > it) {   // strictly-upper 128x128 tile: zeros
        int i = it * 128 + (t >> 1);
        int jb = jt * 128 + (t & 1) * 64;
        u16x8 z = {};
        #pragma unroll
        for (int s = 0; s < 8; s++)
            *reinterpret_cast<u16x8*>(Ap + (size_t)i * CHK + jb + s * 8) = z;
        return;
    }
    int wid = t >> 6, lane = t & 63;
    int wr = wid >> 1, wc = wid & 1;
    int lg = lane >> 4, ln = lane & 15;
    int i0 = it * 128 + wr * 64, j0c = jt * 128 + wc * 64;
    f32x4 acc[4][4] = {};
    const ushort_t* qb = phiQ + ((size_t)(b * L_ + c * CHK + i0 + ln)) * F_ + lg * 8;
    const ushort_t* kb = phiK + ((size_t)(b * L_ + c * CHK + j0c + ln)) * F_ + lg * 8;
    for (int f0 = 0; f0 < F_; f0 += 32) {
        bf16x8 afr[4], bfr[4];
        #pragma unroll
        for (int mt = 0; mt < 4; mt++) afr[mt] = *reinterpret_cast<const bf16x8*>(qb + (size_t)mt * 16 * F_ + f0);
        #pragma unroll
        for (int nt = 0; nt < 4; nt++) bfr[nt] = *reinterpret_cast<const bf16x8*>(kb + (size_t)nt * 16 * F_ + f0);
        #pragma unroll
        for (int mt = 0; mt < 4; mt++)
            #pragma unroll
            for (int nt = 0; nt < 4; nt++)
                acc[mt][nt] = __builtin_amdgcn_mfma_f32_16x16x32_bf16(afr[mt], bfr[nt], acc[mt][nt], 0, 0, 0);
    }
    #pragma unroll
    for (int mt = 0; mt < 4; mt++)
        #pragma unroll
        for (int r = 0; r < 4; r++) {
            int i = i0 + mt * 16 + lg * 4 + r;
            #pragma unroll
            for (int nt = 0; nt < 4; nt++) {
                int j = j0c + nt * 16 + ln;
                Ap[(size_t)i * CHK + j] = (i >= j) ? f2b(acc[mt][nt][r]) : (ushort_t)0;
            }
        }
}

// Fused S-local GEMM + exclusive chunk-scan.
// Stp[b][c][d][f] = sum_{c'<c} sum_{j in c'} V[j][d]*phiK[j][f]  (bf16)
__global__ __launch_bounds__(256) void sloc_k(const ushort_t* __restrict__ Vt,
                                              const ushort_t* __restrict__ phiKT,
                                              ushort_t* __restrict__ Stp) {
    int b = blockIdx.z;
    int dt = blockIdx.y * 64, ft = blockIdx.x * 64;
    int t = threadIdx.x;
    int wid = t >> 6, lane = t & 63;
    int wr = wid >> 1, wc = wid & 1;
    int lg = lane >> 4, ln = lane & 15;
    int d0 = dt + wr * 32, f0 = ft + wc * 32;
    f32x4 acc[2][2] = {};
    const ushort_t* vbase = Vt + ((size_t)(b * D_ + d0 + ln)) * L_ + lg * 8;
    const ushort_t* kbase = phiKT + ((size_t)(b * F_ + f0 + ln)) * L_ + lg * 8;
    for (int c = 0; c < NC; c++) {
        if (c > 0) {   // write exclusive prefix (chunk 0's prefix is zeros & never read)
            ushort_t* sp = Stp + ((size_t)(b * NC + c)) * D_ * F_;
            #pragma unroll
            for (int mt = 0; mt < 2; mt++)
                #pragma unroll
                for (int r = 0; r < 4; r++) {
                    int d = d0 + mt * 16 + lg * 4 + r;
                    #pragma unroll
                    for (int nt = 0; nt < 2; nt++)
                        sp[(size_t)d * F_ + f0 + nt * 16 + ln] = f2b(acc[mt][nt][r]);
                }
        }
        #pragma unroll 2
        for (int j0 = 0; j0 < CHK; j0 += 32) {
            bf16x8 av[2], bv[2];
            #pragma unroll
            for (int mt = 0; mt < 2; mt++) av[mt] = *reinterpret_cast<const bf16x8*>(vbase + (size_t)mt * 16 * L_ + c * CHK + j0);
            #pragma unroll
            for (int nt = 0; nt < 2; nt++) bv[nt] = *reinterpret_cast<const bf16x8*>(kbase + (size_t)nt * 16 * L_ + c * CHK + j0);
            #pragma unroll
            for (int mt = 0; mt < 2; mt++)
                #pragma unroll
                for (int nt = 0; nt < 2; nt++)
                    acc[mt][nt] = __builtin_amdgcn_mfma_f32_16x16x32_bf16(av[mt], bv[nt], acc[mt][nt], 0, 0, 0);
        }
    }
}

// out = (phiQ @ Stp^T + Amat @ Vt^T) / max(phiQ.Zp + rowsum(Amat), eps)
// den computed on the matrix pipe via broadcast-B MFMAs.
__global__ __launch_bounds__(256) void outm_k(const ushort_t* __restrict__ phiQ,
                                              const ushort_t* __restrict__ Stp,
                                              const ushort_t* __restrict__ Amat,
                                              const ushort_t* __restrict__ Vt,
                                              const ushort_t* __restrict__ Zp,
                                              float* __restrict__ out) {
    int bc = blockIdx.z, b = bc >> 4, c = bc & 15;
    int ybase = blockIdx.y * 128;   // chunk-local row block
    int xbase = blockIdx.x * 128;   // d block
    int t = threadIdx.x;
    int wid = t >> 6, lane = t & 63;
    int wr = wid >> 1, wc = wid & 1;
    int lg = lane >> 4, ln = lane & 15;
    int row0 = ybase + wr * 64;
    int d0 = xbase + wc * 64;

    f32x4 acc[4][4] = {};
    f32x4 den[4] = {};

    const ushort_t* qbase = phiQ + ((size_t)(b * L_ + c * CHK + row0 + ln)) * F_ + lg * 8;

    if (c > 0) {
        const ushort_t* sbase = Stp + ((size_t)bc * D_ + d0 + ln) * F_ + lg * 8;
        const ushort_t* zbase = Zp + (size_t)bc * F_ + lg * 8;
        for (int f0 = 0; f0 < F_; f0 += 32) {
            bf16x8 afr[4], bfr[4], zfr;
            #pragma unroll
            for (int mt = 0; mt < 4; mt++) afr[mt] = *reinterpret_cast<const bf16x8*>(qbase + (size_t)mt * 16 * F_ + f0);
            #pragma unroll
            for (int nt = 0; nt < 4; nt++) bfr[nt] = *reinterpret_cast<const bf16x8*>(sbase + (size_t)nt * 16 * F_ + f0);
            zfr = *reinterpret_cast<const bf16x8*>(zbase + f0);
            #pragma unroll
            for (int mt = 0; mt < 4; mt++) {
                den[mt] = __builtin_amdgcn_mfma_f32_16x16x32_bf16(afr[mt], zfr, den[mt], 0, 0, 0);
                #pragma unroll
                for (int nt = 0; nt < 4; nt++)
                    acc[mt][nt] = __builtin_amdgcn_mfma_f32_16x16x32_bf16(afr[mt], bfr[nt], acc[mt][nt], 0, 0, 0);
            }
        }
    }
    {   // intra-chunk: A @ V with causal-limited j range
        const ushort_t* abase = Amat + ((size_t)bc * CHK + row0 + ln) * CHK + lg * 8;
        const ushort_t* vbase = Vt + ((size_t)(b * D_ + d0 + ln)) * L_ + c * CHK + lg * 8;
        bf16x8 ones;
        #pragma unroll
        for (int s = 0; s < 8; s++) ones[s] = (short)0x3F80;   // bf16 1.0
        int jmax = ybase + 128;
        for (int j0 = 0; j0 < jmax; j0 += 32) {
            bf16x8 afr[4], bfr[4];
            #pragma unroll
            for (int mt = 0; mt < 4; mt++) afr[mt] = *reinterpret_cast<const bf16x8*>(abase + (size_t)mt * 16 * CHK + j0);
            #pragma unroll
            for (int nt = 0; nt < 4; nt++) bfr[nt] = *reinterpret_cast<const bf16x8*>(vbase + (size_t)nt * 16 * L_ + j0);
            #pragma unroll
            for (int mt = 0; mt < 4; mt++) {
                den[mt] = __builtin_amdgcn_mfma_f32_16x16x32_bf16(afr[mt], ones, den[mt], 0, 0, 0);
                #pragma unroll
                for (int nt = 0; nt < 4; nt++)
                    acc[mt][nt] = __builtin_amdgcn_mfma_f32_16x16x32_bf16(afr[mt], bfr[nt], acc[mt][nt], 0, 0, 0);
            }
        }
    }
    float* obase = out + ((size_t)(b * L_ + c * CHK + row0)) * D_ + d0;
    #pragma unroll
    for (int mt = 0; mt < 4; mt++)
        #pragma unroll
        for (int r = 0; r < 4; r++) {
            float inv = 1.0f / fmaxf(den[mt][r], EPSF);
            int row = mt * 16 + lg * 4 + r;
            #pragma unroll
            for (int nt = 0; nt < 4; nt++)
                obase[(size_t)row * D_ + nt * 16 + ln] = acc[mt][nt][r] * inv;
        }
}

// ===========================================================================
// FALLBACK fp32 PATH (round-1, known-correct, needs 84 MB ws)
// ===========================================================================
__global__ __launch_bounds__(256) void zlocal_f(const float* __restrict__ keys, float* __restrict__ Z) {
    int bc = blockIdx.y;
    int b = bc / NC, c = bc % NC;
    int f = blockIdx.x * 256 + threadIdx.x;
    const float* kp = keys + ((size_t)b * L_ + (size_t)c * CHK) * F_ + f;
    float s0 = 0.f, s1 = 0.f, s2 = 0.f, s3 = 0.f;
    for (int j = 0; j < CHK; j += 4) {
        s0 += phi_map(kp[(size_t)(j + 0) * F_]);
        s1 += phi_map(kp[(size_t)(j + 1) * F_]);
        s2 += phi_map(kp[(size_t)(j + 2) * F_]);
        s3 += phi_map(kp[(size_t)(j + 3) * F_]);
    }
    Z[(size_t)bc * F_ + f] = (s0 + s1) + (s2 + s3);
}
__global__ __launch_bounds__(256) void zscan_f(float* __restrict__ Z) {
    int t = blockIdx.x * 256 + threadIdx.x;
    int b = t / F_, f = t % F_;
    float tmp[NC];
    for (int c = 0; c < NC; c++) tmp[c] = Z[((size_t)(b * NC + c)) * F_ + f];
    float run = 0.f;
    for (int c = 0; c < NC; c++) { Z[((size_t)(b * NC + c)) * F_ + f] = run; run += tmp[c]; }
}
__global__ __launch_bounds__(256) void slocal_f(const float* __restrict__ keys,
                                                const float* __restrict__ vals,
                                                float* __restrict__ S) {
    int bc = blockIdx.z;
    int b = bc / NC, c = bc % NC;
    int ft0 = blockIdx.y * 64, dt0 = blockIdx.x * 64;
    __shared__ float Ks[16][64];
    __shared__ float Vs[16][64];
    int tid = threadIdx.x, ty = tid >> 4, tx = tid & 15;
    float acc[4][4] = {};
    const float* kbase = keys + ((size_t)b * L_ + (size_t)c * CHK) * F_;
    const float* vbase = vals + ((size_t)b * L_ + (size_t)c * CHK) * D_;
    for (int j0 = 0; j0 < CHK; j0 += 16) {
        int row = tid >> 4, c4 = (tid & 15) * 4;
        float4 kv = *reinterpret_cast<const float4*>(&kbase[(size_t)(j0 + row) * F_ + ft0 + c4]);
        Ks[row][c4 + 0] = phi_map(kv.x); Ks[row][c4 + 1] = phi_map(kv.y);
        Ks[row][c4 + 2] = phi_map(kv.z); Ks[row][c4 + 3] = phi_map(kv.w);
        float4 vv = *reinterpret_cast<const float4*>(&vbase[(size_t)(j0 + row) * D_ + dt0 + c4]);
        *reinterpret_cast<float4*>(&Vs[row][c4]) = vv;
        __syncthreads();
        #pragma unroll
        for (int kk = 0; kk < 16; kk++) {
            float4 a = *reinterpret_cast<const float4*>(&Ks[kk][ty * 4]);
            float4 bb = *reinterpret_cast<const float4*>(&Vs[kk][tx * 4]);
            float av[4] = {a.x, a.y, a.z, a.w};
            float bv[4] = {bb.x, bb.y, bb.z, bb.w};
            #pragma unroll
            for (int i = 0; i < 4; i++)
                #pragma unroll
                for (int j = 0; j < 4; j++) acc[i][j] += av[i] * bv[j];
        }
        __syncthreads();
    }
    float* Sp = S + (size_t)bc * F_ * D_;
    for (int i = 0; i < 4; i++) {
        int f = ft0 + ty * 4 + i;
        float4 st = {acc[i][0], acc[i][1], acc[i][2], acc[i][3]};
        *reinterpret_cast<float4*>(&Sp[(size_t)f * D_ + dt0 + tx * 4]) = st;
    }
}
__global__ __launch_bounds__(256) void sscan_f(float* __restrict__ S) {
    size_t t = (size_t)blockIdx.x * 256 + threadIdx.x;
    int b = (int)(t / (F_ * D_));
    int fd = (int)(t % (F_ * D_));
    float tmp[NC];
    for (int c = 0; c < NC; c++) tmp[c] = S[((size_t)(b * NC + c)) * F_ * D_ + fd];
    float run = 0.f;
    for (int c = 0; c < NC; c++) { S[((size_t)(b * NC + c)) * F_ * D_ + fd] = run; run += tmp[c]; }
}
__global__ __launch_bounds__(256) void amat_f(const float* __restrict__ q,
                                              const float* __restrict__ keys,
                                              float* __restrict__ A) {
    int bc = blockIdx.y;
    int b = bc / NC, c = bc % NC;
    int tt = blockIdx.x;
    int it = (tt >= 6) ? 3 : (tt >= 3) ? 2 : (tt >= 1) ? 1 : 0;
    int jt = tt - it * (it + 1) / 2;
    int i0 = it * 64, j0 = jt * 64;
    __shared__ float Qs[64][17];
    __shared__ float Ks2[64][17];
    int tid = threadIdx.x, ty = tid >> 4, tx = tid & 15;
    float acc[4][4] = {};
    const float* qbase = q + ((size_t)b * L_ + (size_t)c * CHK + i0) * F_;
    const float* kbase = keys + ((size_t)b * L_ + (size_t)c * CHK + j0) * F_;
    for (int f0 = 0; f0 < F_; f0 += 16) {
        int row = tid >> 2, c4 = (tid & 3) * 4;
        float4 qv = *reinterpret_cast<const float4*>(&qbase[(size_t)row * F_ + f0 + c4]);
        Qs[row][c4 + 0] = phi_map(qv.x); Qs[row][c4 + 1] = phi_map(qv.y);
        Qs[row][c4 + 2] = phi_map(qv.z); Qs[row][c4 + 3] = phi_map(qv.w);
        float4 kv = *reinterpret_cast<const float4*>(&kbase[(size_t)row * F_ + f0 + c4]);
        Ks2[row][c4 + 0] = phi_map(kv.x); Ks2[row][c4 + 1] = phi_map(kv.y);
        Ks2[row][c4 + 2] = phi_map(kv.z); Ks2[row][c4 + 3] = phi_map(kv.w);
        __syncthreads();
        #pragma unroll
        for (int kk = 0; kk < 16; kk++) {
            float av[4], bv[4];
            #pragma unroll
            for (int i = 0; i < 4; i++) av[i] = Qs[ty * 4 + i][kk];
            #pragma unroll
            for (int j = 0; j < 4; j++) bv[j] = Ks2[tx * 4 + j][kk];
            #pragma unroll
            for (int i = 0; i < 4; i++)
                #pragma unroll
                for (int j = 0; j < 4; j++) acc[i][j] += av[i] * bv[j];
        }
        __syncthreads();
    }
    float* Ap = A + (size_t)bc * CHK * CHK;
    for (int i = 0; i < 4; i++) {
        int gi = i0 + ty * 4 + i;
        int gj = j0 + tx * 4;
        float4 st;
        st.x = (gi >= gj + 0) ? acc[i][0] : 0.f;
        st.y = (gi >= gj + 1) ? acc[i][1] : 0.f;
        st.z = (gi >= gj + 2) ? acc[i][2] : 0.f;
        st.w = (gi >= gj + 3) ? acc[i][3] : 0.f;
        *reinterpret_cast<float4*>(&Ap[(size_t)gi * CHK + gj]) = st;
    }
}
__global__ __launch_bounds__(256) void out_f(const float* __restrict__ q,
                                             const float* __restrict__ vals,
                                             const float* __restrict__ S,
                                             const float* __restrict__ A,
                                             const float* __restrict__ Z,
                                             float* __restrict__ out) {
    int bc = blockIdx.z;
    int b = bc / NC, c = bc % NC;
    int rt = blockIdx.y;
    int dt0 = blockIdx.x * 64;
    int r0 = rt * 64;
    __shared__ float Ls[64][17];
    __shared__ float Rs[16][64];
    __shared__ float Zs[16];
    int tid = threadIdx.x, ty = tid >> 4, tx = tid & 15;
    float acc[4][4] = {};
    float qz[4] = {};
    float rs[4] = {};
    const float* qbase = q + ((size_t)b * L_ + (size_t)c * CHK + r0) * F_;
    if (c > 0) {
        const float* Sp = S + (size_t)bc * F_ * D_;
        const float* Zp2 = Z + (size_t)bc * F_;
        for (int f0 = 0; f0 < F_; f0 += 16) {
            int row = tid >> 2, c4 = (tid & 3) * 4;
            float4 qv = *reinterpret_cast<const float4*>(&qbase[(size_t)row * F_ + f0 + c4]);
            Ls[row][c4 + 0] = phi_map(qv.x); Ls[row][c4 + 1] = phi_map(qv.y);
            Ls[row][c4 + 2] = phi_map(qv.z); Ls[row][c4 + 3] = phi_map(qv.w);
            int row2 = tid >> 4, d4 = (tid & 15) * 4;
            float4 sv = *reinterpret_cast<const float4*>(&Sp[(size_t)(f0 + row2) * D_ + dt0 + d4]);
            *reinterpret_cast<float4*>(&Rs[row2][d4]) = sv;
            if (tid < 16) Zs[tid] = Zp2[f0 + tid];
            __syncthreads();
            #pragma unroll
            for (int kk = 0; kk < 16; kk++) {
                float av[4];
                #pragma unroll
                for (int i = 0; i < 4; i++) av[i] = Ls[ty * 4 + i][kk];
                float4 bb = *reinterpret_cast<const float4*>(&Rs[kk][tx * 4]);
                float bv[4] = {bb.x, bb.y, bb.z, bb.w};
                float zk = Zs[kk];
                #pragma unroll
                for (int i = 0; i < 4; i++) {
                    qz[i] += av[i] * zk;
                    #pragma unroll
                    for (int j = 0; j < 4; j++) acc[i][j] += av[i] * bv[j];
                }
            }
            __syncthreads();
        }
    }
    const float* Ap = A + (size_t)bc * CHK * CHK;
    const float* vbase = vals + ((size_t)b * L_ + (size_t)c * CHK) * D_;
    for (int j0 = 0; j0 < (rt + 1) * 64; j0 += 16) {
        int row = tid >> 2, c4 = (tid & 3) * 4;
        float4 av4 = *reinterpret_cast<const float4*>(&Ap[(size_t)(r0 + row) * CHK + j0 + c4]);
        Ls[row][c4 + 0] = av4.x; Ls[row][c4 + 1] = av4.y;
        Ls[row][c4 + 2] = av4.z; Ls[row][c4 + 3] = av4.w;
        int row2 = tid >> 4, d4 = (tid & 15) * 4;
        float4 vv = *reinterpret_cast<const float4*>(&vbase[(size_t)(j0 + row2) * D_ + dt0 + d4]);
        *reinterpret_cast<float4*>(&Rs[row2][d4]) = vv;
        __syncthreads();
        #pragma unroll
        for (int kk = 0; kk < 16; kk++) {
            float av[4];
            #pragma unroll
            for (int i = 0; i < 4; i++) av[i] = Ls[ty * 4 + i][kk];
            float4 bb = *reinterpret_cast<const float4*>(&Rs[kk][tx * 4]);
            float bv[4] = {bb.x, bb.y, bb.z, bb.w};
            #pragma unroll
            for (int i = 0; i < 4; i++) {
                rs[i] += av[i];
                #pragma unroll
                for (int j = 0; j < 4; j++) acc[i][j] += av[i] * bv[j];
            }
        }
        __syncthreads();
    }
    float* obase = out + ((size_t)b * L_ + (size_t)c * CHK + r0) * D_ + dt0;
    for (int i = 0; i < 4; i++) {
        float dd = fmaxf(qz[i] + rs[i], EPSF);
        float inv = 1.0f / dd;
        float4 st = {acc[i][0] * inv, acc[i][1] * inv, acc[i][2] * inv, acc[i][3] * inv};
        *reinterpret_cast<float4*>(&obase[(size_t)(ty * 4 + i) * D_ + tx * 4]) = st;
    }
}

// ===========================================================================
extern "C" void kernel_launch(void* const* d_in, const int* in_sizes, int n_in,
                              void* d_out, int out_size, void* d_ws, size_t ws_size,
                              hipStream_t stream) {
    const float* q = (const float*)d_in[0];
    const float* k = (const float*)d_in[1];
    const float* v = (const float*)d_in[2];
    float* out = (float*)d_out;

    // --- bf16 MFMA path sizes (ushort elems) ---
    const size_t nPhi  = (size_t)B_ * L_ * F_;          // 8388608
    const size_t nStp  = (size_t)B_ * NC * D_ * F_;     // 16777216
    const size_t nAmat = (size_t)B_ * NC * CHK * CHK;   // 4194304
    const size_t nZ    = (size_t)B_ * NC * F_;          // 32768
    const size_t totalU = 4 * nPhi + nStp + nAmat + nZ;
    const size_t needNew = totalU * 2 + nZ * 4;

    if (ws_size >= needNew) {
        ushort_t* phiQ  = (ushort_t*)d_ws;
        ushort_t* phiK  = phiQ + nPhi;
        ushort_t* phiKT = phiK + nPhi;
        ushort_t* Vt    = phiKT + nPhi;
        ushort_t* Stp   = Vt + nPhi;
        ushort_t* Amat  = Stp + nStp;
        ushort_t* Zp    = Amat + nAmat;
        float*    Zloc  = (float*)(Zp + nZ);

        prepq_k<<<dim3((unsigned)(nPhi / 8 / 256)), 256, 0, stream>>>(q, phiQ);
        prepkt_k<<<dim3(F_ / 64, L_ / 64, B_), 256, 0, stream>>>(k, phiK, phiKT);
        prepvt_k<<<dim3(D_ / 64, L_ / 64, B_), 256, 0, stream>>>(v, Vt);
        zloc_k<<<dim3(B_ * NC), 256, 0, stream>>>(phiK, Zloc);
        zscan_k<<<dim3((B_ * F_) / 256), 256, 0, stream>>>(Zloc, Zp);
        amatm_k<<<dim3(2, 2, B_ * NC), 256, 0, stream>>>(phiQ, phiK, Amat);
        sloc_k<<<dim3(F_ / 64, D_ / 64, B_), 256, 0, stream>>>(Vt, phiKT, Stp);
        outm_k<<<dim3(D_ / 128, CHK / 128, B_ * NC), 256, 0, stream>>>(phiQ, Stp, Amat, Vt, Zp, out);
        return;
    }

    // --- fallback fp32 path ---
    size_t nS = (size_t)B_ * NC * F_ * D_;
    size_t nA = (size_t)B_ * NC * CHK * CHK;
    size_t nZf = (size_t)B_ * NC * F_;
    size_t need = (nS + nA + nZf) * sizeof(float);
    if (ws_size < need) return;
    float* S = (float*)d_ws;
    float* A = S + nS;
    float* Z = A + nA;
    zlocal_f<<<dim3(F_ / 256, B_ * NC), 256, 0, stream>>>(k, Z);
    slocal_f<<<dim3(D_ / 64, F_ / 64, B_ * NC), 256, 0, stream>>>(k, v, S);
    amat_f<<<dim3(10, B_ * NC), 256, 0, stream>>>(q, k, A);
    zscan_f<<<dim3((B_ * F_) / 256), 256, 0, stream>>>(Z);
    sscan_f<<<dim3((B_ * F_ * D_) / 256), 256, 0, stream>>>(S);
    out_f<<<dim3(D_ / 64, CHK / 64, B_ * NC), 256, 0, stream>>>(q, v, S, A, Z, out);
}